// Round 1
// baseline (305.367 us; speedup 1.0000x reference)
//
#include <hip/hip_runtime.h>
#include <math.h>

#define B 4
#define T 128
#define C 512
#define NH 8
#define HS 64
#define BH (B*NH)   // 32

// ---------------- GEMM 512x512x512: P = X @ W, head-major output ----------------
__global__ __launch_bounds__(256) void gemm_proj_kernel(
    const float* __restrict__ X,
    const float* __restrict__ W0, const float* __restrict__ W1, const float* __restrict__ W2,
    float* __restrict__ P0, float* __restrict__ P1, float* __restrict__ P2)
{
    __shared__ float As[16][68];
    __shared__ float Bs[16][68];
    const int which = blockIdx.z;
    const float* W = (which == 0) ? W0 : (which == 1) ? W1 : W2;
    float* P = (which == 0) ? P0 : (which == 1) ? P1 : P2;
    const int m0 = blockIdx.y * 64, n0 = blockIdx.x * 64;
    const int tid = threadIdx.x;
    const int tx = tid & 15, ty = tid >> 4;
    const int arow = tid >> 2, acol = (tid & 3) * 4;
    const int brow = tid >> 4, bcol = (tid & 15) * 4;
    float acc[4][4] = {};
    for (int k0 = 0; k0 < 512; k0 += 16) {
        const float4 av = *(const float4*)&X[(size_t)(m0 + arow) * 512 + k0 + acol];
        const float4 bv = *(const float4*)&W[(size_t)(k0 + brow) * 512 + n0 + bcol];
        __syncthreads();
        As[acol + 0][arow] = av.x;
        As[acol + 1][arow] = av.y;
        As[acol + 2][arow] = av.z;
        As[acol + 3][arow] = av.w;
        *(float4*)&Bs[brow][bcol] = bv;
        __syncthreads();
        #pragma unroll
        for (int kk = 0; kk < 16; ++kk) {
            const float4 a4 = *(const float4*)&As[kk][ty * 4];
            const float4 b4 = *(const float4*)&Bs[kk][tx * 4];
            const float ar[4] = {a4.x, a4.y, a4.z, a4.w};
            const float br[4] = {b4.x, b4.y, b4.z, b4.w};
            #pragma unroll
            for (int r = 0; r < 4; ++r)
                #pragma unroll
                for (int c = 0; c < 4; ++c)
                    acc[r][c] = fmaf(ar[r], br[c], acc[r][c]);
        }
    }
    #pragma unroll
    for (int r = 0; r < 4; ++r) {
        const int m = m0 + ty * 4 + r;
        const int b = m >> 7, t = m & 127;
        #pragma unroll
        for (int c = 0; c < 4; ++c) {
            const int n = n0 + tx * 4 + c;
            const int h = n >> 6, d = n & 63;
            P[(((size_t)(b * NH + h) * T + t) * HS) + d] = acc[r][c];
        }
    }
}

// ---------------- GEMM 512x512x512: OUT = Yb @ Wc, row-major output ----------------
__global__ __launch_bounds__(256) void gemm_out_kernel(
    const float* __restrict__ X, const float* __restrict__ W, float* __restrict__ OUT)
{
    __shared__ float As[16][68];
    __shared__ float Bs[16][68];
    const int m0 = blockIdx.y * 64, n0 = blockIdx.x * 64;
    const int tid = threadIdx.x;
    const int tx = tid & 15, ty = tid >> 4;
    const int arow = tid >> 2, acol = (tid & 3) * 4;
    const int brow = tid >> 4, bcol = (tid & 15) * 4;
    float acc[4][4] = {};
    for (int k0 = 0; k0 < 512; k0 += 16) {
        const float4 av = *(const float4*)&X[(size_t)(m0 + arow) * 512 + k0 + acol];
        const float4 bv = *(const float4*)&W[(size_t)(k0 + brow) * 512 + n0 + bcol];
        __syncthreads();
        As[acol + 0][arow] = av.x;
        As[acol + 1][arow] = av.y;
        As[acol + 2][arow] = av.z;
        As[acol + 3][arow] = av.w;
        *(float4*)&Bs[brow][bcol] = bv;
        __syncthreads();
        #pragma unroll
        for (int kk = 0; kk < 16; ++kk) {
            const float4 a4 = *(const float4*)&As[kk][ty * 4];
            const float4 b4 = *(const float4*)&Bs[kk][tx * 4];
            const float ar[4] = {a4.x, a4.y, a4.z, a4.w};
            const float br[4] = {b4.x, b4.y, b4.z, b4.w};
            #pragma unroll
            for (int r = 0; r < 4; ++r)
                #pragma unroll
                for (int c = 0; c < 4; ++c)
                    acc[r][c] = fmaf(ar[r], br[c], acc[r][c]);
        }
    }
    #pragma unroll
    for (int r = 0; r < 4; ++r) {
        const int m = m0 + ty * 4 + r;
        #pragma unroll
        for (int c = 0; c < 4; ++c) {
            const int n = n0 + tx * 4 + c;
            OUT[(size_t)m * 512 + n] = acc[r][c];
        }
    }
}

// ---------------- per-head V = P @ Wv (T x HS @ HS x HS) ----------------
__global__ __launch_bounds__(256) void vproj_kernel(
    const float* __restrict__ P, const float* __restrict__ Wv, float* __restrict__ V)
{
    __shared__ float sW[HS * HS];
    const int bh = blockIdx.x, tid = threadIdx.x;
    for (int q = tid; q < HS * HS / 4; q += 256)
        ((float4*)sW)[q] = ((const float4*)Wv)[q];
    __syncthreads();
    const int d = tid & 63, tg = tid >> 6;
    const float* Pb = P + (size_t)bh * T * HS;
    float* Vb = V + (size_t)bh * T * HS;
    for (int t = tg; t < T; t += 4) {
        const float* prow = Pb + t * HS;
        float acc = 0.f;
        #pragma unroll
        for (int e = 0; e < HS; ++e) acc = fmaf(prow[e], sW[e * HS + d], acc);
        Vb[t * HS + d] = acc;
    }
}

// ---------------- r[k] = rowsum(p2), prefix max/min ----------------
__global__ __launch_bounds__(128) void r_kernel(
    const float* __restrict__ P2, float* __restrict__ RR,
    float* __restrict__ RPX, float* __restrict__ RPN)
{
    __shared__ float srr[T];
    const int bh = blockIdx.x, t = threadIdx.x;
    const float* row = P2 + ((size_t)bh * T + t) * HS;
    float acc = 0.f;
    #pragma unroll
    for (int e = 0; e < HS; ++e) acc += row[e];
    srr[t] = acc;
    RR[bh * T + t] = acc;
    __syncthreads();
    if (t == 0) {
        float mx = -INFINITY, mn = INFINITY;
        for (int k = 0; k < T; ++k) {
            mx = fmaxf(mx, srr[k]);
            mn = fminf(mn, srr[k]);
            RPX[bh * T + k] = mx;
            RPN[bh * T + k] = mn;
        }
    }
}

// ---------------- main higher-order attention: one block per (b,h,i) ----------------
__global__ __launch_bounds__(256) void attn_kernel(
    const float* __restrict__ P0, const float* __restrict__ P1,
    const float* __restrict__ V0, const float* __restrict__ V1,
    const float* __restrict__ RR, const float* __restrict__ RPX, const float* __restrict__ RPN,
    float* __restrict__ Y)
{
    __shared__ float sV1[T * HS];   // 32 KB
    __shared__ float sS[T];
    __shared__ float sr[T];
    __shared__ float sred[256];
    __shared__ float syacc[3 * HS];
    __shared__ float sz[4];

    const int blk = blockIdx.x;
    const int bh = blk & (BH - 1);
    const int i = (T - 1) - (blk >> 5);   // descending i: big blocks launch first
    const int tid = threadIdx.x;
    const int w = tid >> 6;               // wave 0..3
    const int lane = tid & 63;

    const float* p1b = P1 + (size_t)bh * T * HS;
    const float* v0b = V0 + (size_t)bh * T * HS;
    const float* v1b = V1 + (size_t)bh * T * HS;

    // stage V1 rows [0, i] into LDS (coalesced float4)
    const int n4 = (i + 1) * (HS / 4);
    const float4* v1g = (const float4*)v1b;
    for (int q = tid; q < n4; q += 256) ((float4*)sV1)[q] = v1g[q];

    // stage r
    if (tid <= i) sr[tid] = RR[bh * T + tid];

    // per-lane p0[i, lane]
    const float p0v = P0[((size_t)bh * T + i) * HS + lane];

    // S row: wave w handles j = w, w+4, ... ; butterfly-reduce over 64 lanes
    for (int j = w; j <= i; j += 4) {
        float v = p0v * p1b[j * HS + lane];
        #pragma unroll
        for (int off = 32; off > 0; off >>= 1) v += __shfl_xor(v, off, 64);
        if (lane == 0) sS[j] = v * 0.125f;
    }
    __syncthreads();

    // m_i = max over valid (j,k) of S_ij * r_k, via r prefix max/min
    float cand = -INFINITY;
    if (tid <= i) {
        const float Sj = sS[tid];
        cand = (Sj >= 0.f) ? Sj * RPX[bh * T + tid] : Sj * RPN[bh * T + tid];
    }
    sred[tid] = cand;
    __syncthreads();
    for (int s = 128; s > 0; s >>= 1) {
        if (tid < s) sred[tid] = fmaxf(sred[tid], sred[tid + s]);
        __syncthreads();
    }
    const float m = sred[0];

    const float L2E = 1.4426950408889634f;
    const float bexp = -m * L2E;
    float yacc = 0.f, zacc = 0.f;
    for (int j = w; j <= i; j += 4) {
        const float a = sS[j] * L2E;
        float tacc = 0.f;
        #pragma unroll 4
        for (int k = 0; k <= j; ++k) {
            const float e = __builtin_amdgcn_exp2f(fmaf(a, sr[k], bexp));
            zacc += e;                                   // same on all lanes
            tacc = fmaf(e, sV1[k * HS + lane], tacc);
        }
        yacc = fmaf(v0b[j * HS + lane], tacc, yacc);
    }

    if (w > 0) syacc[(w - 1) * HS + lane] = yacc;
    if (lane == 0) sz[w] = zacc;
    __syncthreads();
    if (w == 0) {
        const float tot = yacc + syacc[lane] + syacc[HS + lane] + syacc[2 * HS + lane];
        const float Z = sz[0] + sz[1] + sz[2] + sz[3];
        const int b = bh >> 3, h = bh & 7;
        Y[(size_t)(b * T + i) * C + h * HS + lane] = tot / Z;
    }
}

extern "C" void kernel_launch(void* const* d_in, const int* in_sizes, int n_in,
                              void* d_out, int out_size, void* d_ws, size_t ws_size,
                              hipStream_t stream)
{
    const float* x   = (const float*)d_in[0];
    const float* Wp0 = (const float*)d_in[1];
    const float* Wp1 = (const float*)d_in[2];
    const float* Wp2 = (const float*)d_in[3];
    const float* Wv0 = (const float*)d_in[4];
    const float* Wv1 = (const float*)d_in[5];
    const float* Wc  = (const float*)d_in[6];
    float* out = (float*)d_out;

    float* ws = (float*)d_ws;
    const size_t PSZ = (size_t)BH * T * HS; // 262144
    float* p0 = ws;
    float* p1 = p0 + PSZ;
    float* p2 = p1 + PSZ;
    float* V0 = p2 + PSZ;
    float* V1 = V0 + PSZ;
    float* yb = V1 + PSZ;
    float* rr = yb + PSZ;
    float* rpx = rr + BH * T;
    float* rpn = rpx + BH * T;

    gemm_proj_kernel<<<dim3(8, 8, 3), 256, 0, stream>>>(x, Wp0, Wp1, Wp2, p0, p1, p2);
    vproj_kernel<<<dim3(BH), 256, 0, stream>>>(p1, Wv0, V0);
    vproj_kernel<<<dim3(BH), 256, 0, stream>>>(p2, Wv1, V1);
    r_kernel<<<dim3(BH), T, 0, stream>>>(p2, rr, rpx, rpn);
    attn_kernel<<<dim3(BH * T), 256, 0, stream>>>(p0, p1, V0, V1, rr, rpx, rpn, yb);
    gemm_out_kernel<<<dim3(8, 8), 256, 0, stream>>>(yb, Wc, out);
}

// Round 2
// 189.658 us; speedup vs baseline: 1.6101x; 1.6101x over previous
//
#include <hip/hip_runtime.h>
#include <hip/hip_bf16.h>
#include <math.h>

#define B 4
#define T 128
#define C 512
#define NH 8
#define HS 64
#define BH (B*NH)   // 32

typedef __attribute__((ext_vector_type(8))) short bf16x8;
typedef __attribute__((ext_vector_type(4))) float f32x4;

__device__ __forceinline__ unsigned short bfc(float x) {
    return __builtin_bit_cast(unsigned short, __float2bfloat16(x));
}

// ---------------- weight combine: We = Wp @ blockdiag(Wv)  (per z slice) ----------------
__global__ __launch_bounds__(256) void wcomb_kernel(
    const float* __restrict__ Wp1, const float* __restrict__ Wp2,
    const float* __restrict__ Wv0, const float* __restrict__ Wv1,
    float* __restrict__ We0, float* __restrict__ We1)
{
    __shared__ float As[16][68];
    __shared__ float Bs[16][68];
    const float* A  = blockIdx.z ? Wp2 : Wp1;
    const float* Wv = blockIdx.z ? Wv1 : Wv0;
    float* O        = blockIdx.z ? We1 : We0;
    const int h = blockIdx.x;          // head = 64-col tile
    const int m0 = blockIdx.y * 64;
    const int tid = threadIdx.x;
    const int tx = tid & 15, ty = tid >> 4;
    const int arow = tid >> 2, acol = (tid & 3) * 4;
    const int brow = tid >> 4, bcol = (tid & 15) * 4;
    float acc[4][4] = {};
    for (int k0 = 0; k0 < 64; k0 += 16) {
        const float4 av = *(const float4*)&A[(size_t)(m0 + arow) * 512 + h * 64 + k0 + acol];
        const float4 bv = *(const float4*)&Wv[(size_t)(k0 + brow) * 64 + bcol];
        __syncthreads();
        As[acol + 0][arow] = av.x;
        As[acol + 1][arow] = av.y;
        As[acol + 2][arow] = av.z;
        As[acol + 3][arow] = av.w;
        *(float4*)&Bs[brow][bcol] = bv;
        __syncthreads();
        #pragma unroll
        for (int kk = 0; kk < 16; ++kk) {
            const float4 a4 = *(const float4*)&As[kk][ty * 4];
            const float4 b4 = *(const float4*)&Bs[kk][tx * 4];
            const float ar[4] = {a4.x, a4.y, a4.z, a4.w};
            const float br[4] = {b4.x, b4.y, b4.z, b4.w};
            #pragma unroll
            for (int r = 0; r < 4; ++r)
                #pragma unroll
                for (int c = 0; c < 4; ++c)
                    acc[r][c] = fmaf(ar[r], br[c], acc[r][c]);
        }
    }
    #pragma unroll
    for (int r = 0; r < 4; ++r)
        #pragma unroll
        for (int c = 0; c < 4; ++c)
            O[(size_t)(m0 + ty * 4 + r) * 512 + h * 64 + tx * 4 + c] = acc[r][c];
}

// ---------------- 5-way projection GEMM: p0,p1,p2,V0 (fp32 head-major), V1T (bf16 transposed) ----------------
__global__ __launch_bounds__(256) void proj5_kernel(
    const float* __restrict__ X,
    const float* __restrict__ Wp0, const float* __restrict__ Wp1, const float* __restrict__ Wp2,
    const float* __restrict__ We0, const float* __restrict__ We1,
    float* __restrict__ P0, float* __restrict__ P1, float* __restrict__ P2,
    float* __restrict__ V0, unsigned short* __restrict__ V1T)
{
    __shared__ float As[16][68];
    __shared__ float Bs[16][68];
    const int z = blockIdx.z;
    const float* W = (z == 0) ? Wp0 : (z == 1) ? Wp1 : (z == 2) ? Wp2 : (z == 3) ? We0 : We1;
    const int m0 = blockIdx.y * 64, n0 = blockIdx.x * 64;
    const int tid = threadIdx.x;
    const int tx = tid & 15, ty = tid >> 4;
    const int arow = tid >> 2, acol = (tid & 3) * 4;
    const int brow = tid >> 4, bcol = (tid & 15) * 4;
    float acc[4][4] = {};
    for (int k0 = 0; k0 < 512; k0 += 16) {
        const float4 av = *(const float4*)&X[(size_t)(m0 + arow) * 512 + k0 + acol];
        const float4 bv = *(const float4*)&W[(size_t)(k0 + brow) * 512 + n0 + bcol];
        __syncthreads();
        As[acol + 0][arow] = av.x;
        As[acol + 1][arow] = av.y;
        As[acol + 2][arow] = av.z;
        As[acol + 3][arow] = av.w;
        *(float4*)&Bs[brow][bcol] = bv;
        __syncthreads();
        #pragma unroll
        for (int kk = 0; kk < 16; ++kk) {
            const float4 a4 = *(const float4*)&As[kk][ty * 4];
            const float4 b4 = *(const float4*)&Bs[kk][tx * 4];
            const float ar[4] = {a4.x, a4.y, a4.z, a4.w};
            const float br[4] = {b4.x, b4.y, b4.z, b4.w};
            #pragma unroll
            for (int r = 0; r < 4; ++r)
                #pragma unroll
                for (int c = 0; c < 4; ++c)
                    acc[r][c] = fmaf(ar[r], br[c], acc[r][c]);
        }
    }
    float* Ps = (z == 0) ? P0 : (z == 1) ? P1 : (z == 2) ? P2 : V0;
    #pragma unroll
    for (int r = 0; r < 4; ++r) {
        const int m = m0 + ty * 4 + r;
        const int b = m >> 7, t = m & 127;
        #pragma unroll
        for (int c = 0; c < 4; ++c) {
            const int n = n0 + tx * 4 + c;
            const int h = n >> 6, d = n & 63;
            if (z < 4) {
                Ps[(((size_t)(b * NH + h) * T + t) * HS) + d] = acc[r][c];
            } else {
                V1T[(((size_t)(b * NH + h) * HS + d) * T) + t] = bfc(acc[r][c]);
            }
        }
    }
}

// ---------------- batched S = P0 @ P1^T * 0.125 per (b,h), bf16 MFMA ----------------
__global__ __launch_bounds__(256) void sgemm_kernel(
    const float* __restrict__ P0, const float* __restrict__ P1, float* __restrict__ Sg)
{
    __shared__ __align__(16) unsigned short sA[128][72];
    __shared__ __align__(16) unsigned short sB[128][72];
    const int bh = blockIdx.x;
    const int tid = threadIdx.x;
    const int w = tid >> 6, lane = tid & 63, quad = lane >> 4, l16 = lane & 15;
    const float* p0 = P0 + (size_t)bh * T * HS;
    const float* p1 = P1 + (size_t)bh * T * HS;
    #pragma unroll
    for (int it = 0; it < 8; ++it) {
        const int q = tid + it * 256;
        const int row = q >> 4, c4 = (q & 15) << 2;
        const float4 v = *(const float4*)&p0[row * 64 + c4];
        uint2 pk;
        pk.x = (unsigned int)bfc(v.x) | ((unsigned int)bfc(v.y) << 16);
        pk.y = (unsigned int)bfc(v.z) | ((unsigned int)bfc(v.w) << 16);
        *(uint2*)&sA[row][c4] = pk;
        const float4 u = *(const float4*)&p1[row * 64 + c4];
        uint2 qk;
        qk.x = (unsigned int)bfc(u.x) | ((unsigned int)bfc(u.y) << 16);
        qk.y = (unsigned int)bfc(u.z) | ((unsigned int)bfc(u.w) << 16);
        *(uint2*)&sB[row][c4] = qk;
    }
    __syncthreads();
    f32x4 acc[2][8];
    #pragma unroll
    for (int a = 0; a < 2; ++a)
        #pragma unroll
        for (int b = 0; b < 8; ++b)
            acc[a][b] = (f32x4){0.f, 0.f, 0.f, 0.f};
    #pragma unroll
    for (int kt = 0; kt < 2; ++kt) {
        const bf16x8 a0 = *(const bf16x8*)&sA[(2 * w) * 16 + l16][kt * 32 + quad * 8];
        const bf16x8 a1 = *(const bf16x8*)&sA[(2 * w + 1) * 16 + l16][kt * 32 + quad * 8];
        #pragma unroll
        for (int nt = 0; nt < 8; ++nt) {
            const bf16x8 b8 = *(const bf16x8*)&sB[nt * 16 + l16][kt * 32 + quad * 8];
            acc[0][nt] = __builtin_amdgcn_mfma_f32_16x16x32_bf16(a0, b8, acc[0][nt], 0, 0, 0);
            acc[1][nt] = __builtin_amdgcn_mfma_f32_16x16x32_bf16(a1, b8, acc[1][nt], 0, 0, 0);
        }
    }
    #pragma unroll
    for (int mt2 = 0; mt2 < 2; ++mt2)
        #pragma unroll
        for (int nt = 0; nt < 8; ++nt)
            #pragma unroll
            for (int r = 0; r < 4; ++r) {
                const int row = (2 * w + mt2) * 16 + quad * 4 + r;
                const int col = nt * 16 + l16;
                Sg[((size_t)bh * T + row) * T + col] = acc[mt2][nt][r] * 0.125f;
            }
}

// ---------------- r[k] = rowsum(p2), prefix max/min ----------------
__global__ __launch_bounds__(128) void r_kernel(
    const float* __restrict__ P2, float* __restrict__ RR,
    float* __restrict__ RPX, float* __restrict__ RPN)
{
    __shared__ float srr[T];
    const int bh = blockIdx.x, t = threadIdx.x;
    const float* row = P2 + ((size_t)bh * T + t) * HS;
    float acc = 0.f;
    #pragma unroll
    for (int e = 0; e < HS; ++e) acc += row[e];
    srr[t] = acc;
    RR[bh * T + t] = acc;
    __syncthreads();
    if (t == 0) {
        float mx = -INFINITY, mn = INFINITY;
        for (int k = 0; k < T; ++k) {
            mx = fmaxf(mx, srr[k]);
            mn = fminf(mn, srr[k]);
            RPX[bh * T + k] = mx;
            RPN[bh * T + k] = mn;
        }
    }
}

// ---------------- main attention: one block per (b,h,i); E@V1 via MFMA ----------------
__global__ __launch_bounds__(256) void attn_kernel(
    const float* __restrict__ Sg, const float* __restrict__ RR,
    const float* __restrict__ RPX, const float* __restrict__ RPN,
    const float* __restrict__ V0g, const unsigned short* __restrict__ V1Tg,
    float* __restrict__ Y)
{
    __shared__ __align__(16) unsigned short sE[128][136];   // 34816 B
    __shared__ __align__(16) unsigned short sV1T[64][136];  // 17408 B
    __shared__ float sS[T];
    __shared__ float sr[T];
    __shared__ float sM[4];
    __shared__ float sZ[4];

    const int blk = blockIdx.x;
    const int bh = blk & (BH - 1);
    const int i = (T - 1) - (blk >> 5);     // descending i: big blocks first
    const int tid = threadIdx.x;
    const int w = tid >> 6;
    const int lane = tid & 63;
    const int quad = lane >> 4;
    const int l16 = lane & 15;

    // stage S row, r row
    if (tid < T) {
        sS[tid] = Sg[((size_t)bh * T + i) * T + tid];
        sr[tid] = RR[bh * T + tid];
    }
    // stage V1T (64 d-rows x 128 k-cols, bf16): 1024 16B chunks
    {
        const unsigned short* src = V1Tg + (size_t)bh * HS * T;
        #pragma unroll
        for (int it = 0; it < 4; ++it) {
            const int q = tid + it * 256;
            const int d = q >> 4, c8 = (q & 15) << 3;
            *(uint4*)&sV1T[d][c8] = *(const uint4*)&src[d * T + c8];
        }
    }
    __syncthreads();

    // exact max m = max_{j<=i} f(S_j) with r prefix max/min
    float cand = -INFINITY;
    if (tid <= i) {
        const float Sj = sS[tid];
        cand = (Sj >= 0.f) ? Sj * RPX[bh * T + tid] : Sj * RPN[bh * T + tid];
    }
    #pragma unroll
    for (int off = 32; off; off >>= 1) cand = fmaxf(cand, __shfl_xor(cand, off, 64));
    if (lane == 0) sM[w] = cand;
    __syncthreads();
    const float m = fmaxf(fmaxf(sM[0], sM[1]), fmaxf(sM[2], sM[3]));

    // build E (bf16) rows j<=i; zero where k>j; accumulate Z
    const float L2E = 1.4426950408889634f;
    const float bexp = -m * L2E;
    float zacc = 0.f;
    {
        const int jrow = tid >> 1;
        const int c0 = (tid & 1) << 6;
        if (jrow <= i) {
            const float a = sS[jrow] * L2E;
            #pragma unroll 8
            for (int c = 0; c < 64; c += 2) {
                const int k0 = c0 + c;
                float e0 = __builtin_amdgcn_exp2f(fmaf(a, sr[k0], bexp));
                float e1 = __builtin_amdgcn_exp2f(fmaf(a, sr[k0 + 1], bexp));
                e0 = (k0 <= jrow) ? e0 : 0.f;
                e1 = (k0 + 1 <= jrow) ? e1 : 0.f;
                zacc += e0 + e1;
                const unsigned int u0 = bfc(e0);
                const unsigned int u1 = bfc(e1);
                *(unsigned int*)&sE[jrow][k0] = (u1 << 16) | u0;
            }
        }
    }
    #pragma unroll
    for (int off = 32; off; off >>= 1) zacc += __shfl_xor(zacc, off, 64);
    if (lane == 0) sZ[w] = zacc;
    __syncthreads();
    const float Z = sZ[0] + sZ[1] + sZ[2] + sZ[3];

    // Tmat = E @ V1 : wave w covers 16 d-columns
    const int n0 = w << 4;
    f32x4 acc[8];
    #pragma unroll
    for (int mt = 0; mt < 8; ++mt) acc[mt] = (f32x4){0.f, 0.f, 0.f, 0.f};
    #pragma unroll
    for (int kt = 0; kt < 4; ++kt) {
        const bf16x8 b8 = *(const bf16x8*)&sV1T[n0 + l16][(kt << 5) + (quad << 3)];
        #pragma unroll
        for (int mt = 0; mt < 8; ++mt) {
            const bf16x8 a8 = *(const bf16x8*)&sE[(mt << 4) + l16][(kt << 5) + (quad << 3)];
            acc[mt] = __builtin_amdgcn_mfma_f32_16x16x32_bf16(a8, b8, acc[mt], 0, 0, 0);
        }
    }

    // epilogue: y[d] = sum_j V0[j][d] * Tmat[j][d] / Z
    const float* v0b = V0g + (size_t)bh * T * HS;
    const int d = n0 + l16;
    float part = 0.f;
    #pragma unroll
    for (int mt = 0; mt < 8; ++mt) {
        #pragma unroll
        for (int r = 0; r < 4; ++r) {
            const int j = (mt << 4) + (quad << 2) + r;
            const float contrib = (j <= i) ? v0b[j * HS + d] * acc[mt][r] : 0.f;
            part += contrib;
        }
    }
    part += __shfl_xor(part, 16, 64);
    part += __shfl_xor(part, 32, 64);
    if (lane < 16) {
        const int b = bh >> 3, h = bh & 7;
        Y[((size_t)(b * T + i) * C) + h * HS + d] = part / Z;
    }
}

// ---------------- OUT = Yb @ Wc ----------------
__global__ __launch_bounds__(256) void gemm_out_kernel(
    const float* __restrict__ X, const float* __restrict__ W, float* __restrict__ OUT)
{
    __shared__ float As[16][68];
    __shared__ float Bs[16][68];
    const int m0 = blockIdx.y * 64, n0 = blockIdx.x * 64;
    const int tid = threadIdx.x;
    const int tx = tid & 15, ty = tid >> 4;
    const int arow = tid >> 2, acol = (tid & 3) * 4;
    const int brow = tid >> 4, bcol = (tid & 15) * 4;
    float acc[4][4] = {};
    for (int k0 = 0; k0 < 512; k0 += 16) {
        const float4 av = *(const float4*)&X[(size_t)(m0 + arow) * 512 + k0 + acol];
        const float4 bv = *(const float4*)&W[(size_t)(k0 + brow) * 512 + n0 + bcol];
        __syncthreads();
        As[acol + 0][arow] = av.x;
        As[acol + 1][arow] = av.y;
        As[acol + 2][arow] = av.z;
        As[acol + 3][arow] = av.w;
        *(float4*)&Bs[brow][bcol] = bv;
        __syncthreads();
        #pragma unroll
        for (int kk = 0; kk < 16; ++kk) {
            const float4 a4 = *(const float4*)&As[kk][ty * 4];
            const float4 b4 = *(const float4*)&Bs[kk][tx * 4];
            const float ar[4] = {a4.x, a4.y, a4.z, a4.w};
            const float br[4] = {b4.x, b4.y, b4.z, b4.w};
            #pragma unroll
            for (int r = 0; r < 4; ++r)
                #pragma unroll
                for (int c = 0; c < 4; ++c)
                    acc[r][c] = fmaf(ar[r], br[c], acc[r][c]);
        }
    }
    #pragma unroll
    for (int r = 0; r < 4; ++r)
        #pragma unroll
        for (int c = 0; c < 4; ++c)
            OUT[(size_t)(m0 + ty * 4 + r) * 512 + n0 + tx * 4 + c] = acc[r][c];
}

extern "C" void kernel_launch(void* const* d_in, const int* in_sizes, int n_in,
                              void* d_out, int out_size, void* d_ws, size_t ws_size,
                              hipStream_t stream)
{
    const float* x   = (const float*)d_in[0];
    const float* Wp0 = (const float*)d_in[1];
    const float* Wp1 = (const float*)d_in[2];
    const float* Wp2 = (const float*)d_in[3];
    const float* Wv0 = (const float*)d_in[4];
    const float* Wv1 = (const float*)d_in[5];
    const float* Wc  = (const float*)d_in[6];
    float* out = (float*)d_out;

    float* ws = (float*)d_ws;
    const size_t PSZ = (size_t)BH * T * HS; // 262144
    float* p0 = ws;
    float* p1 = p0 + PSZ;
    float* p2 = p1 + PSZ;
    float* V0 = p2 + PSZ;
    float* yb = V0 + PSZ;
    float* We0 = yb + PSZ;
    float* We1 = We0 + PSZ;
    float* Sg = We0;                                // alias: Sg (2*PSZ) reuses We0/We1 after proj5
    unsigned short* V1T = (unsigned short*)(We1 + PSZ);
    float* rr  = (float*)(V1T + PSZ);
    float* rpx = rr + BH * T;
    float* rpn = rpx + BH * T;

    wcomb_kernel<<<dim3(8, 8, 2), 256, 0, stream>>>(Wp1, Wp2, Wv0, Wv1, We0, We1);
    proj5_kernel<<<dim3(8, 8, 5), 256, 0, stream>>>(x, Wp0, Wp1, Wp2, We0, We1,
                                                    p0, p1, p2, V0, V1T);
    sgemm_kernel<<<dim3(BH), 256, 0, stream>>>(p0, p1, Sg);
    r_kernel<<<dim3(BH), T, 0, stream>>>(p2, rr, rpx, rpn);
    attn_kernel<<<dim3(BH * T), 256, 0, stream>>>(Sg, rr, rpx, rpn, V0, V1T, yb);
    gemm_out_kernel<<<dim3(8, 8), 256, 0, stream>>>(yb, Wc, out);
}

// Round 3
// 138.357 us; speedup vs baseline: 2.2071x; 1.3708x over previous
//
#include <hip/hip_runtime.h>
#include <hip/hip_bf16.h>
#include <math.h>

#define B 4
#define T 128
#define C 512
#define NH 8
#define HS 64
#define BH (B*NH)   // 32

typedef __attribute__((ext_vector_type(8))) short bf16x8;
typedef __attribute__((ext_vector_type(4))) float f32x4;

__device__ __forceinline__ unsigned short bfc(float x) {
    return __builtin_bit_cast(unsigned short, __float2bfloat16(x));
}
__device__ __forceinline__ float b2f(unsigned short u) {
    unsigned int x = ((unsigned int)u) << 16;
    return __builtin_bit_cast(float, x);
}
__device__ __forceinline__ float sum8(uint4 u) {
    float s = 0.f;
    s += b2f((unsigned short)(u.x & 0xffff)); s += b2f((unsigned short)(u.x >> 16));
    s += b2f((unsigned short)(u.y & 0xffff)); s += b2f((unsigned short)(u.y >> 16));
    s += b2f((unsigned short)(u.z & 0xffff)); s += b2f((unsigned short)(u.z >> 16));
    s += b2f((unsigned short)(u.w & 0xffff)); s += b2f((unsigned short)(u.w >> 16));
    return s;
}

// ---------------- convert: X -> bf16 rowmajor; Wp0/Wp1/Wp2/Wc -> bf16 transposed ----------------
__global__ __launch_bounds__(256) void cvt_kernel(
    const float* __restrict__ X, const float* __restrict__ Wp0, const float* __restrict__ Wp1,
    const float* __restrict__ Wp2, const float* __restrict__ Wc,
    unsigned short* __restrict__ Xb, unsigned short* __restrict__ W0T, unsigned short* __restrict__ W1T,
    unsigned short* __restrict__ W2T, unsigned short* __restrict__ WcT)
{
    const int z = blockIdx.z;
    const int r0 = blockIdx.y * 64, c0 = blockIdx.x * 64;
    const int tid = threadIdx.x;
    if (z == 0) {
        #pragma unroll
        for (int it = 0; it < 2; ++it) {
            const int q = tid + it * 256;
            const int row = q >> 3, c8 = (q & 7) * 8;
            const float4 a = *(const float4*)&X[(size_t)(r0 + row) * 512 + c0 + c8];
            const float4 b = *(const float4*)&X[(size_t)(r0 + row) * 512 + c0 + c8 + 4];
            uint4 o;
            o.x = (unsigned int)bfc(a.x) | ((unsigned int)bfc(a.y) << 16);
            o.y = (unsigned int)bfc(a.z) | ((unsigned int)bfc(a.w) << 16);
            o.z = (unsigned int)bfc(b.x) | ((unsigned int)bfc(b.y) << 16);
            o.w = (unsigned int)bfc(b.z) | ((unsigned int)bfc(b.w) << 16);
            *(uint4*)&Xb[(size_t)(r0 + row) * 512 + c0 + c8] = o;
        }
        return;
    }
    __shared__ float Ls[64][69];
    const float* W = (z == 1) ? Wp0 : (z == 2) ? Wp1 : (z == 3) ? Wp2 : Wc;
    unsigned short* WT = (z == 1) ? W0T : (z == 2) ? W1T : (z == 3) ? W2T : WcT;
    #pragma unroll
    for (int it = 0; it < 4; ++it) {
        const int q = tid + it * 256;
        const int row = q >> 4, c4 = (q & 15) * 4;
        const float4 v = *(const float4*)&W[(size_t)(r0 + row) * 512 + c0 + c4];
        Ls[row][c4 + 0] = v.x; Ls[row][c4 + 1] = v.y; Ls[row][c4 + 2] = v.z; Ls[row][c4 + 3] = v.w;
    }
    __syncthreads();
    #pragma unroll
    for (int it = 0; it < 2; ++it) {
        const int q = tid + it * 256;
        const int nrow = q >> 3, k8 = (q & 7) * 8;
        uint4 o;
        o.x = (unsigned int)bfc(Ls[k8 + 0][nrow]) | ((unsigned int)bfc(Ls[k8 + 1][nrow]) << 16);
        o.y = (unsigned int)bfc(Ls[k8 + 2][nrow]) | ((unsigned int)bfc(Ls[k8 + 3][nrow]) << 16);
        o.z = (unsigned int)bfc(Ls[k8 + 4][nrow]) | ((unsigned int)bfc(Ls[k8 + 5][nrow]) << 16);
        o.w = (unsigned int)bfc(Ls[k8 + 6][nrow]) | ((unsigned int)bfc(Ls[k8 + 7][nrow]) << 16);
        *(uint4*)&WT[(size_t)(c0 + nrow) * 512 + r0 + k8] = o;
    }
}

// ---------------- We = Wp @ blockdiag(Wv), output transposed bf16 ----------------
__global__ __launch_bounds__(256) void wcomb_kernel(
    const float* __restrict__ Wp1, const float* __restrict__ Wp2,
    const float* __restrict__ Wv0, const float* __restrict__ Wv1,
    unsigned short* __restrict__ We0T, unsigned short* __restrict__ We1T)
{
    __shared__ float As[16][68];
    __shared__ float Bs[16][68];
    const float* A  = blockIdx.z ? Wp2 : Wp1;
    const float* Wv = blockIdx.z ? Wv1 : Wv0;
    unsigned short* O = blockIdx.z ? We1T : We0T;
    const int h = blockIdx.x;
    const int m0 = blockIdx.y * 64;
    const int tid = threadIdx.x;
    const int tx = tid & 15, ty = tid >> 4;
    const int arow = tid >> 2, acol = (tid & 3) * 4;
    const int brow = tid >> 4, bcol = (tid & 15) * 4;
    float acc[4][4] = {};
    for (int k0 = 0; k0 < 64; k0 += 16) {
        const float4 av = *(const float4*)&A[(size_t)(m0 + arow) * 512 + h * 64 + k0 + acol];
        const float4 bv = *(const float4*)&Wv[(size_t)(k0 + brow) * 64 + bcol];
        __syncthreads();
        As[acol + 0][arow] = av.x; As[acol + 1][arow] = av.y;
        As[acol + 2][arow] = av.z; As[acol + 3][arow] = av.w;
        *(float4*)&Bs[brow][bcol] = bv;
        __syncthreads();
        #pragma unroll
        for (int kk = 0; kk < 16; ++kk) {
            const float4 a4 = *(const float4*)&As[kk][ty * 4];
            const float4 b4 = *(const float4*)&Bs[kk][tx * 4];
            const float ar[4] = {a4.x, a4.y, a4.z, a4.w};
            const float br[4] = {b4.x, b4.y, b4.z, b4.w};
            #pragma unroll
            for (int r = 0; r < 4; ++r)
                #pragma unroll
                for (int c = 0; c < 4; ++c)
                    acc[r][c] = fmaf(ar[r], br[c], acc[r][c]);
        }
    }
    #pragma unroll
    for (int r = 0; r < 4; ++r)
        #pragma unroll
        for (int c = 0; c < 4; ++c)
            O[(size_t)(h * 64 + tx * 4 + c) * 512 + (m0 + ty * 4 + r)] = bfc(acc[r][c]);
}

// ---------------- bf16 MFMA projection GEMM: 5 slices ----------------
__global__ __launch_bounds__(256) void projmm_kernel(
    const unsigned short* __restrict__ Xb,
    const unsigned short* __restrict__ W0T, const unsigned short* __restrict__ W1T,
    const unsigned short* __restrict__ W2T,
    const unsigned short* __restrict__ We0T, const unsigned short* __restrict__ We1T,
    unsigned short* __restrict__ p0b, unsigned short* __restrict__ p1b, unsigned short* __restrict__ p2b,
    float* __restrict__ V0, unsigned short* __restrict__ V1T)
{
    __shared__ __align__(16) unsigned short As[64][72];
    __shared__ __align__(16) unsigned short Bs[64][72];
    const int z = blockIdx.z;
    const unsigned short* WT = (z == 0) ? W0T : (z == 1) ? W1T : (z == 2) ? W2T : (z == 3) ? We0T : We1T;
    const int m0 = blockIdx.y * 64, n0 = blockIdx.x * 64;
    const int tid = threadIdx.x;
    const int w = tid >> 6, lane = tid & 63, quad = lane >> 4, l16 = lane & 15;
    f32x4 acc[4];
    #pragma unroll
    for (int mt = 0; mt < 4; ++mt) acc[mt] = (f32x4){0.f, 0.f, 0.f, 0.f};
    for (int k0 = 0; k0 < 512; k0 += 64) {
        __syncthreads();
        #pragma unroll
        for (int it = 0; it < 2; ++it) {
            const int q = tid + it * 256;
            const int row = q >> 3, c8 = (q & 7) * 8;
            *(uint4*)&As[row][c8] = *(const uint4*)&Xb[(size_t)(m0 + row) * 512 + k0 + c8];
            *(uint4*)&Bs[row][c8] = *(const uint4*)&WT[(size_t)(n0 + row) * 512 + k0 + c8];
        }
        __syncthreads();
        #pragma unroll
        for (int kt = 0; kt < 2; ++kt) {
            const bf16x8 b8 = *(const bf16x8*)&Bs[w * 16 + l16][kt * 32 + quad * 8];
            #pragma unroll
            for (int mt = 0; mt < 4; ++mt) {
                const bf16x8 a8 = *(const bf16x8*)&As[mt * 16 + l16][kt * 32 + quad * 8];
                acc[mt] = __builtin_amdgcn_mfma_f32_16x16x32_bf16(a8, b8, acc[mt], 0, 0, 0);
            }
        }
    }
    const int n = n0 + w * 16 + l16;
    const int h = n >> 6, d = n & 63;
    #pragma unroll
    for (int mt = 0; mt < 4; ++mt) {
        #pragma unroll
        for (int r = 0; r < 4; ++r) {
            const int m = m0 + mt * 16 + quad * 4 + r;
            const int b = m >> 7, t = m & 127;
            const size_t hm = (size_t)(b * NH + h) * T + t;
            const float v = acc[mt][r];
            if (z == 0)      p0b[hm * HS + d] = bfc(v);
            else if (z == 1) p1b[hm * HS + d] = bfc(v);
            else if (z == 2) p2b[hm * HS + d] = bfc(v);
            else if (z == 3) V0[hm * HS + d] = v;
            else             V1T[((size_t)(b * NH + h) * HS + d) * T + t] = bfc(v);
        }
    }
}

// ---------------- S = P0 @ P1^T * 0.125 (bf16 out) + r rowsum/prefix, per bh ----------------
__global__ __launch_bounds__(256) void sgemm_kernel(
    const unsigned short* __restrict__ p0b, const unsigned short* __restrict__ p1b,
    const unsigned short* __restrict__ p2b,
    unsigned short* __restrict__ Sgb, float* __restrict__ RR,
    float* __restrict__ RPX, float* __restrict__ RPN)
{
    __shared__ __align__(16) unsigned short sA[128][72];
    __shared__ __align__(16) unsigned short sB[128][72];
    __shared__ float srr[128];
    const int bh = blockIdx.x;
    const int tid = threadIdx.x;
    const int w = tid >> 6, lane = tid & 63, quad = lane >> 4, l16 = lane & 15;
    // r = rowsum(p2)
    {
        const int row = tid >> 1, half = tid & 1;
        const unsigned short* pr = p2b + ((size_t)bh * T + row) * HS + half * 32;
        float s = 0.f;
        #pragma unroll
        for (int c = 0; c < 32; c += 8) s += sum8(*(const uint4*)&pr[c]);
        s += __shfl_xor(s, 1, 64);
        if (half == 0) srr[row] = s;
    }
    #pragma unroll
    for (int it = 0; it < 4; ++it) {
        const int q = tid + it * 256;
        const int row = q >> 3, c8 = (q & 7) * 8;
        *(uint4*)&sA[row][c8] = *(const uint4*)&p0b[(size_t)bh * T * HS + row * 64 + c8];
        *(uint4*)&sB[row][c8] = *(const uint4*)&p1b[(size_t)bh * T * HS + row * 64 + c8];
    }
    __syncthreads();
    if (tid == 0) {
        float mx = -INFINITY, mn = INFINITY;
        for (int k = 0; k < T; ++k) {
            const float v = srr[k];
            mx = fmaxf(mx, v); mn = fminf(mn, v);
            RR[bh * T + k] = v; RPX[bh * T + k] = mx; RPN[bh * T + k] = mn;
        }
    }
    f32x4 acc[2][8];
    #pragma unroll
    for (int a = 0; a < 2; ++a)
        #pragma unroll
        for (int b = 0; b < 8; ++b) acc[a][b] = (f32x4){0.f, 0.f, 0.f, 0.f};
    #pragma unroll
    for (int kt = 0; kt < 2; ++kt) {
        const bf16x8 a0 = *(const bf16x8*)&sA[(2 * w) * 16 + l16][kt * 32 + quad * 8];
        const bf16x8 a1 = *(const bf16x8*)&sA[(2 * w + 1) * 16 + l16][kt * 32 + quad * 8];
        #pragma unroll
        for (int nt = 0; nt < 8; ++nt) {
            const bf16x8 b8 = *(const bf16x8*)&sB[nt * 16 + l16][kt * 32 + quad * 8];
            acc[0][nt] = __builtin_amdgcn_mfma_f32_16x16x32_bf16(a0, b8, acc[0][nt], 0, 0, 0);
            acc[1][nt] = __builtin_amdgcn_mfma_f32_16x16x32_bf16(a1, b8, acc[1][nt], 0, 0, 0);
        }
    }
    #pragma unroll
    for (int mt2 = 0; mt2 < 2; ++mt2)
        #pragma unroll
        for (int nt = 0; nt < 8; ++nt)
            #pragma unroll
            for (int r = 0; r < 4; ++r) {
                const int row = (2 * w + mt2) * 16 + quad * 4 + r;
                const int col = nt * 16 + l16;
                Sgb[((size_t)bh * T + row) * T + col] = bfc(acc[mt2][nt][r] * 0.125f);
            }
}

// ---------------- main attention ----------------
__global__ __launch_bounds__(256) void attn_kernel(
    const unsigned short* __restrict__ Sgb, const float* __restrict__ RR,
    const float* __restrict__ RPX, const float* __restrict__ RPN,
    const float* __restrict__ V0g, const unsigned short* __restrict__ V1Tg,
    unsigned short* __restrict__ Yb)
{
    __shared__ __align__(16) unsigned short sE[128 * 128];  // 32 KB, xor-swizzled 16B chunks
    __shared__ float sS[T];
    __shared__ float sM[4];
    __shared__ float sZ[4];

    const int blk = blockIdx.x;
    const int bh = blk & (BH - 1);
    const int i = (T - 1) - (blk >> 5);
    const int tid = threadIdx.x;
    const int w = tid >> 6;
    const int lane = tid & 63;
    const int quad = lane >> 4;
    const int l16 = lane & 15;

    if (tid < T) sS[tid] = b2f(Sgb[((size_t)bh * T + i) * T + tid]);
    const float2 rv = *(const float2*)&RR[bh * T + 2 * lane];
    // V1 B-fragments in registers: wave w covers d = w*16+l16
    uint4 v1r[4];
    {
        const unsigned short* src = V1Tg + ((size_t)bh * HS + w * 16 + l16) * T;
        #pragma unroll
        for (int kt = 0; kt < 4; ++kt)
            v1r[kt] = *(const uint4*)&src[kt * 32 + quad * 8];
    }
    __syncthreads();

    // exact max m
    float cand = -INFINITY;
    if (tid <= i) {
        const float Sj = sS[tid];
        cand = (Sj >= 0.f) ? Sj * RPX[bh * T + tid] : Sj * RPN[bh * T + tid];
    }
    #pragma unroll
    for (int off = 32; off; off >>= 1) cand = fmaxf(cand, __shfl_xor(cand, off, 64));
    if (lane == 0) sM[w] = cand;
    __syncthreads();
    const float m = fmaxf(fmaxf(sM[0], sM[1]), fmaxf(sM[2], sM[3]));

    // E-build: column-major ownership (lane -> cols 2l,2l+1), row wave-uniform, swizzled writes
    const float L2E = 1.4426950408889634f;
    const float bexp = -m * L2E;
    const int mtmax = i >> 4;
    const int jmax = (mtmax << 4) + 15;
    const int chunkb = lane >> 2;
    const int inoff = (lane & 3) << 2;
    const int k0 = 2 * lane, k1 = 2 * lane + 1;
    float zacc = 0.f;
    for (int j = w; j <= jmax; j += 4) {
        unsigned int pk = 0;
        if (j <= i) {
            const float aL = sS[j] * L2E;
            float e0 = __builtin_amdgcn_exp2f(fmaf(aL, rv.x, bexp));
            float e1 = __builtin_amdgcn_exp2f(fmaf(aL, rv.y, bexp));
            e0 = (k0 <= j) ? e0 : 0.f;
            e1 = (k1 <= j) ? e1 : 0.f;
            zacc += e0 + e1;
            pk = (unsigned int)bfc(e0) | ((unsigned int)bfc(e1) << 16);
        }
        const int swz = chunkb ^ (j & 15);
        *(unsigned int*)((char*)sE + (j << 8) + (swz << 4) + inoff) = pk;
    }
    #pragma unroll
    for (int off = 32; off; off >>= 1) zacc += __shfl_xor(zacc, off, 64);
    if (lane == 0) sZ[w] = zacc;
    __syncthreads();
    const float Z = sZ[0] + sZ[1] + sZ[2] + sZ[3];

    // Tmat = E @ V1, triangular tiles; wave w covers d-cols [16w,16w+16)
    f32x4 acc[8];
    #pragma unroll
    for (int mt = 0; mt < 8; ++mt) acc[mt] = (f32x4){0.f, 0.f, 0.f, 0.f};
    #pragma unroll
    for (int mt = 0; mt < 8; ++mt) {
        if (mt <= mtmax) {
            #pragma unroll
            for (int kt = 0; kt <= (mt >> 1); ++kt) {
                const int swz = (4 * kt + quad) ^ l16;
                const bf16x8 a8 = *(const bf16x8*)((char*)sE + (((mt << 4) + l16) << 8) + (swz << 4));
                acc[mt] = __builtin_amdgcn_mfma_f32_16x16x32_bf16(
                    a8, __builtin_bit_cast(bf16x8, v1r[kt]), acc[mt], 0, 0, 0);
            }
        }
    }

    // epilogue
    const float* v0b = V0g + (size_t)bh * T * HS;
    const int d = (w << 4) + l16;
    float part = 0.f;
    #pragma unroll
    for (int mt = 0; mt < 8; ++mt) {
        if (mt <= mtmax) {
            #pragma unroll
            for (int r = 0; r < 4; ++r) {
                const int j = (mt << 4) + (quad << 2) + r;
                if (j <= i) part = fmaf(v0b[j * HS + d], acc[mt][r], part);
            }
        }
    }
    part += __shfl_xor(part, 16, 64);
    part += __shfl_xor(part, 32, 64);
    if (lane < 16) {
        const int b = bh >> 3, h = bh & 7;
        Yb[((size_t)(b * T + i) * C) + h * HS + d] = bfc(part / Z);
    }
}

// ---------------- OUT = Yb @ Wc (bf16 MFMA, fp32 out) ----------------
__global__ __launch_bounds__(256) void outmm_kernel(
    const unsigned short* __restrict__ Ab, const unsigned short* __restrict__ WT,
    float* __restrict__ OUT)
{
    __shared__ __align__(16) unsigned short As[64][72];
    __shared__ __align__(16) unsigned short Bs[64][72];
    const int m0 = blockIdx.y * 64, n0 = blockIdx.x * 64;
    const int tid = threadIdx.x;
    const int w = tid >> 6, lane = tid & 63, quad = lane >> 4, l16 = lane & 15;
    f32x4 acc[4];
    #pragma unroll
    for (int mt = 0; mt < 4; ++mt) acc[mt] = (f32x4){0.f, 0.f, 0.f, 0.f};
    for (int k0 = 0; k0 < 512; k0 += 64) {
        __syncthreads();
        #pragma unroll
        for (int it = 0; it < 2; ++it) {
            const int q = tid + it * 256;
            const int row = q >> 3, c8 = (q & 7) * 8;
            *(uint4*)&As[row][c8] = *(const uint4*)&Ab[(size_t)(m0 + row) * 512 + k0 + c8];
            *(uint4*)&Bs[row][c8] = *(const uint4*)&WT[(size_t)(n0 + row) * 512 + k0 + c8];
        }
        __syncthreads();
        #pragma unroll
        for (int kt = 0; kt < 2; ++kt) {
            const bf16x8 b8 = *(const bf16x8*)&Bs[w * 16 + l16][kt * 32 + quad * 8];
            #pragma unroll
            for (int mt = 0; mt < 4; ++mt) {
                const bf16x8 a8 = *(const bf16x8*)&As[mt * 16 + l16][kt * 32 + quad * 8];
                acc[mt] = __builtin_amdgcn_mfma_f32_16x16x32_bf16(a8, b8, acc[mt], 0, 0, 0);
            }
        }
    }
    const int n = n0 + w * 16 + l16;
    #pragma unroll
    for (int mt = 0; mt < 4; ++mt)
        #pragma unroll
        for (int r = 0; r < 4; ++r) {
            const int mrow = m0 + mt * 16 + quad * 4 + r;
            OUT[(size_t)mrow * 512 + n] = acc[mt][r];
        }
}

extern "C" void kernel_launch(void* const* d_in, const int* in_sizes, int n_in,
                              void* d_out, int out_size, void* d_ws, size_t ws_size,
                              hipStream_t stream)
{
    const float* x   = (const float*)d_in[0];
    const float* Wp0 = (const float*)d_in[1];
    const float* Wp1 = (const float*)d_in[2];
    const float* Wp2 = (const float*)d_in[3];
    const float* Wv0 = (const float*)d_in[4];
    const float* Wv1 = (const float*)d_in[5];
    const float* Wc  = (const float*)d_in[6];
    float* out = (float*)d_out;

    char* w8 = (char*)d_ws;
    const size_t HB = 512 * 1024;   // 512 KB
    unsigned short* We0T = (unsigned short*)(w8 + 0 * HB);
    unsigned short* We1T = (unsigned short*)(w8 + 1 * HB);
    unsigned short* Xb   = (unsigned short*)(w8 + 2 * HB);
    unsigned short* W0T  = (unsigned short*)(w8 + 3 * HB);
    unsigned short* W1T  = (unsigned short*)(w8 + 4 * HB);
    unsigned short* W2T  = (unsigned short*)(w8 + 5 * HB);
    unsigned short* WcT  = (unsigned short*)(w8 + 6 * HB);
    unsigned short* p0b  = (unsigned short*)(w8 + 7 * HB);
    unsigned short* p1b  = (unsigned short*)(w8 + 8 * HB);
    unsigned short* p2b  = (unsigned short*)(w8 + 9 * HB);
    float*          V0   = (float*)        (w8 + 10 * HB);   // 1 MB
    unsigned short* V1T  = (unsigned short*)(w8 + 12 * HB);
    unsigned short* Yb   = (unsigned short*)(w8 + 13 * HB);
    float*          rr   = (float*)        (w8 + 14 * HB);
    float*          rpx  = rr + BH * T;
    float*          rpn  = rpx + BH * T;
    unsigned short* Sgb  = (unsigned short*)(w8 + 0);        // 1 MB, aliases We0T/We1T (dead after projmm)

    cvt_kernel  <<<dim3(8, 8, 5), 256, 0, stream>>>(x, Wp0, Wp1, Wp2, Wc, Xb, W0T, W1T, W2T, WcT);
    wcomb_kernel<<<dim3(8, 8, 2), 256, 0, stream>>>(Wp1, Wp2, Wv0, Wv1, We0T, We1T);
    projmm_kernel<<<dim3(8, 8, 5), 256, 0, stream>>>(Xb, W0T, W1T, W2T, We0T, We1T,
                                                     p0b, p1b, p2b, V0, V1T);
    sgemm_kernel<<<dim3(BH), 256, 0, stream>>>(p0b, p1b, p2b, Sgb, rr, rpx, rpn);
    attn_kernel <<<dim3(BH * T), 256, 0, stream>>>(Sgb, rr, rpx, rpn, V0, V1T, Yb);
    outmm_kernel<<<dim3(8, 8), 256, 0, stream>>>(Yb, WcT, out);
}